// Round 1
// baseline (187.734 us; speedup 1.0000x reference)
//
#include <hip/hip_runtime.h>
#include <hip/hip_bf16.h>

// Problem constants
#define NB 32
#define NT 1024
#define ND 256
#define DT 16      // d-columns per transform block
#define LDP 16     // LDS row pitch (floats)
#define ETA 0.1f
#define INVS 0.70710678118654752440f

typedef short bf16x8 __attribute__((ext_vector_type(8)));   // 8 bf16 in 4 VGPRs
typedef float f32x4  __attribute__((ext_vector_type(4)));

__device__ inline unsigned short f2bf(float f){
  __hip_bfloat16 h = __float2bfloat16(f);
  return *reinterpret_cast<unsigned short*>(&h);
}
__device__ inline float bf2f(unsigned short u){
  return __uint_as_float(((unsigned int)u) << 16);
}

// ---------------- in-place Haar butterfly stages (LDS tile: NT x DT, pitch LDP) ----------------
// IDWT stage: a[0..N) + d[N..2N) -> interleaved a'[0..2N)
template<int N>
__device__ inline void idwt_stage(float* lds, int tid){
  constexpr int ITEMS = N * DT;
  if constexpr (ITEMS >= 256) {
    constexpr int PER = ITEMS / 256;
    float ev[PER], ov[PER];
#pragma unroll
    for (int r = 0; r < PER; ++r){
      int idx = tid + r*256; int k = idx >> 4, dc = idx & 15;
      float a = lds[k*LDP + dc];
      float d = lds[(N + k)*LDP + dc];
      ev[r] = (a + d) * INVS; ov[r] = (a - d) * INVS;
    }
    __syncthreads();
#pragma unroll
    for (int r = 0; r < PER; ++r){
      int idx = tid + r*256; int k = idx >> 4, dc = idx & 15;
      lds[(2*k)*LDP + dc]     = ev[r];
      lds[(2*k + 1)*LDP + dc] = ov[r];
    }
    __syncthreads();
  } else {
    float ev = 0.f, ov = 0.f;
    int k = tid >> 4, dc = tid & 15;
    bool act = tid < ITEMS;
    if (act){
      float a = lds[k*LDP + dc];
      float d = lds[(N + k)*LDP + dc];
      ev = (a + d) * INVS; ov = (a - d) * INVS;
    }
    __syncthreads();
    if (act){
      lds[(2*k)*LDP + dc]     = ev;
      lds[(2*k + 1)*LDP + dc] = ov;
    }
    __syncthreads();
  }
}

__device__ inline void idwt_all(float* lds, int tid){
  idwt_stage<1>(lds, tid);   idwt_stage<2>(lds, tid);   idwt_stage<4>(lds, tid);
  idwt_stage<8>(lds, tid);   idwt_stage<16>(lds, tid);  idwt_stage<32>(lds, tid);
  idwt_stage<64>(lds, tid);  idwt_stage<128>(lds, tid); idwt_stage<256>(lds, tid);
  idwt_stage<512>(lds, tid);
}

// DWT stage: interleaved x[0..2N) -> a[0..N) + d[N..2N)
template<int N>
__device__ inline void dwt_stage(float* lds, int tid){
  constexpr int ITEMS = N * DT;
  if constexpr (ITEMS >= 256) {
    constexpr int PER = ITEMS / 256;
    float av[PER], dv[PER];
#pragma unroll
    for (int r = 0; r < PER; ++r){
      int idx = tid + r*256; int k = idx >> 4, dc = idx & 15;
      float e = lds[(2*k)*LDP + dc];
      float o = lds[(2*k + 1)*LDP + dc];
      av[r] = (e + o) * INVS; dv[r] = (e - o) * INVS;
    }
    __syncthreads();
#pragma unroll
    for (int r = 0; r < PER; ++r){
      int idx = tid + r*256; int k = idx >> 4, dc = idx & 15;
      lds[k*LDP + dc]       = av[r];
      lds[(N + k)*LDP + dc] = dv[r];
    }
    __syncthreads();
  } else {
    float av = 0.f, dv = 0.f;
    int k = tid >> 4, dc = tid & 15;
    bool act = tid < ITEMS;
    if (act){
      float e = lds[(2*k)*LDP + dc];
      float o = lds[(2*k + 1)*LDP + dc];
      av = (e + o) * INVS; dv = (e - o) * INVS;
    }
    __syncthreads();
    if (act){
      lds[k*LDP + dc]       = av;
      lds[(N + k)*LDP + dc] = dv;
    }
    __syncthreads();
  }
}

__device__ inline void dwt_all(float* lds, int tid){
  dwt_stage<512>(lds, tid); dwt_stage<256>(lds, tid); dwt_stage<128>(lds, tid);
  dwt_stage<64>(lds, tid);  dwt_stage<32>(lds, tid);  dwt_stage<16>(lds, tid);
  dwt_stage<8>(lds, tid);   dwt_stage<4>(lds, tid);   dwt_stage<2>(lds, tid);
  dwt_stage<1>(lds, tid);
}

// ---------------- kernel A: c = w.rho (write), S = bf16(IDWT(c)) ----------------
__global__ __launch_bounds__(256) void k_idwt_first(const float* __restrict__ rho,
                                                    const float* __restrict__ w,
                                                    float* __restrict__ c,
                                                    unsigned short* __restrict__ S){
  __shared__ float lds[NT * LDP];
  int tid = threadIdx.x;
  int b = blockIdx.y;
  int d0 = blockIdx.x * DT;
  size_t base = ((size_t)b * NT) * ND;
#pragma unroll
  for (int r = 0; r < 16; ++r){
    int q = tid + r*256; int t = q >> 2, qq = q & 3;
    size_t g = base + (size_t)t*ND + d0 + qq*4;
    float4 rv = *(const float4*)(rho + g);
    float4 wv = *(const float4*)(w + (size_t)t*ND + d0 + qq*4);
    float4 cv; cv.x = rv.x*wv.x; cv.y = rv.y*wv.y; cv.z = rv.z*wv.z; cv.w = rv.w*wv.w;
    *(float4*)(c + g) = cv;
    *(float4*)(&lds[t*LDP + qq*4]) = cv;
  }
  __syncthreads();
  idwt_all(lds, tid);
#pragma unroll
  for (int r = 0; r < 16; ++r){
    int q = tid + r*256; int t = q >> 2, qq = q & 3;
    size_t g = base + (size_t)t*ND + d0 + qq*4;
    float4 v = *(float4*)(&lds[t*LDP + qq*4]);
    ushort4 o; o.x = f2bf(v.x); o.y = f2bf(v.y); o.z = f2bf(v.z); o.w = f2bf(v.w);
    *(ushort4*)(S + g) = o;
  }
}

// ---------------- kernel B/D: per-band GEMM  Y[t,:] = S[t,:] @ W[band(t)] + bias ----------------
// Wt is W transposed per band: Wt[band][e][d] = W[band][d][e] (bf16)
__global__ __launch_bounds__(256) void k_band_gemm(const unsigned short* __restrict__ S,
                                                   const unsigned short* __restrict__ Wt,
                                                   const float* __restrict__ bias,
                                                   unsigned short* __restrict__ Y){
  int tile = blockIdx.x;  // 0..36
  int b = blockIdx.y;
  int wv = threadIdx.x >> 6, lane = threadIdx.x & 63;
  int band, t0, lo, hi;
  if (tile < 6){           // masked tiles over rows [0,32): bands 0..5
    band = tile; t0 = 0;
    lo = (band == 0) ? 0 : (1 << (band - 1));
    hi = (band == 0) ? 1 : (1 << band);
  } else {                 // uniform tiles from t0=32
    t0 = (tile - 5) * 32;
    band = 32 - __clz(t0);
    lo = t0; hi = t0 + 32;
  }
  int n0 = wv * 64;
  int row = lane & 15, kg = lane >> 4;
  f32x4 acc[2][4];
#pragma unroll
  for (int mi = 0; mi < 2; ++mi)
#pragma unroll
    for (int ni = 0; ni < 4; ++ni) acc[mi][ni] = (f32x4){0.f, 0.f, 0.f, 0.f};

  const unsigned short* Wb = Wt + (size_t)band * 65536;
  size_t arow0 = ((size_t)b * NT + t0 + row) * ND;
#pragma unroll
  for (int kk = 0; kk < 8; ++kk){
    int k = kk*32 + kg*8;
    bf16x8 a0 = *(const bf16x8*)(S + arow0 + k);
    bf16x8 a1 = *(const bf16x8*)(S + arow0 + 16*ND + k);
#pragma unroll
    for (int ni = 0; ni < 4; ++ni){
      bf16x8 bw = *(const bf16x8*)(Wb + (size_t)(n0 + 16*ni + row)*256 + k);
      acc[0][ni] = __builtin_amdgcn_mfma_f32_16x16x32_bf16(a0, bw, acc[0][ni], 0, 0, 0);
      acc[1][ni] = __builtin_amdgcn_mfma_f32_16x16x32_bf16(a1, bw, acc[1][ni], 0, 0, 0);
    }
  }
#pragma unroll
  for (int ni = 0; ni < 4; ++ni){
    float bv = bias[band*256 + n0 + 16*ni + row];
#pragma unroll
    for (int mi = 0; mi < 2; ++mi){
#pragma unroll
      for (int j = 0; j < 4; ++j){
        int t = t0 + 16*mi + kg*4 + j;   // C/D: row=(lane>>4)*4+reg, col=lane&15
        if (t >= lo && t < hi){
          Y[((size_t)b*NT + t)*ND + n0 + 16*ni + row] = f2bf(acc[mi][ni][j] + bv);
        }
      }
    }
  }
}

// ---------------- kernel C: C2 = DWT(Y); c' = c - eta*(c - C2) (write back); S = bf16(IDWT(c')) ----------------
__global__ __launch_bounds__(256) void k_dwt_update_idwt(const unsigned short* __restrict__ Y,
                                                         float* __restrict__ c,
                                                         unsigned short* __restrict__ S){
  __shared__ float lds[NT * LDP];
  int tid = threadIdx.x;
  int b = blockIdx.y;
  int d0 = blockIdx.x * DT;
  size_t base = ((size_t)b * NT) * ND;
#pragma unroll
  for (int r = 0; r < 16; ++r){
    int q = tid + r*256; int t = q >> 2, qq = q & 3;
    size_t g = base + (size_t)t*ND + d0 + qq*4;
    ushort4 yv = *(const ushort4*)(Y + g);
    lds[t*LDP + qq*4 + 0] = bf2f(yv.x);
    lds[t*LDP + qq*4 + 1] = bf2f(yv.y);
    lds[t*LDP + qq*4 + 2] = bf2f(yv.z);
    lds[t*LDP + qq*4 + 3] = bf2f(yv.w);
  }
  __syncthreads();
  dwt_all(lds, tid);
#pragma unroll
  for (int r = 0; r < 16; ++r){
    int q = tid + r*256; int t = q >> 2, qq = q & 3;
    size_t g = base + (size_t)t*ND + d0 + qq*4;
    float4 cv = *(const float4*)(c + g);
    float4 x  = *(float4*)(&lds[t*LDP + qq*4]);
    float4 nc;
    nc.x = cv.x - ETA*(cv.x - x.x);
    nc.y = cv.y - ETA*(cv.y - x.y);
    nc.z = cv.z - ETA*(cv.z - x.z);
    nc.w = cv.w - ETA*(cv.w - x.w);
    *(float4*)(c + g) = nc;
    *(float4*)(&lds[t*LDP + qq*4]) = nc;
  }
  __syncthreads();
  idwt_all(lds, tid);
#pragma unroll
  for (int r = 0; r < 16; ++r){
    int q = tid + r*256; int t = q >> 2, qq = q & 3;
    size_t g = base + (size_t)t*ND + d0 + qq*4;
    float4 v = *(float4*)(&lds[t*LDP + qq*4]);
    ushort4 o; o.x = f2bf(v.x); o.y = f2bf(v.y); o.z = f2bf(v.z); o.w = f2bf(v.w);
    *(ushort4*)(S + g) = o;
  }
}

// ---------------- kernel E: C2 = DWT(Y); out = (c - eta*(c - C2)) / w ----------------
__global__ __launch_bounds__(256) void k_dwt_final(const unsigned short* __restrict__ Y,
                                                   float* __restrict__ c,
                                                   const float* __restrict__ w){
  __shared__ float lds[NT * LDP];
  int tid = threadIdx.x;
  int b = blockIdx.y;
  int d0 = blockIdx.x * DT;
  size_t base = ((size_t)b * NT) * ND;
#pragma unroll
  for (int r = 0; r < 16; ++r){
    int q = tid + r*256; int t = q >> 2, qq = q & 3;
    size_t g = base + (size_t)t*ND + d0 + qq*4;
    ushort4 yv = *(const ushort4*)(Y + g);
    lds[t*LDP + qq*4 + 0] = bf2f(yv.x);
    lds[t*LDP + qq*4 + 1] = bf2f(yv.y);
    lds[t*LDP + qq*4 + 2] = bf2f(yv.z);
    lds[t*LDP + qq*4 + 3] = bf2f(yv.w);
  }
  __syncthreads();
  dwt_all(lds, tid);
#pragma unroll
  for (int r = 0; r < 16; ++r){
    int q = tid + r*256; int t = q >> 2, qq = q & 3;
    size_t g = base + (size_t)t*ND + d0 + qq*4;
    float4 cv = *(const float4*)(c + g);
    float4 x  = *(float4*)(&lds[t*LDP + qq*4]);
    size_t wg = (size_t)t*ND + d0 + qq*4;
    float4 wv = *(const float4*)(w + wg);
    float4 ov;
    ov.x = (cv.x - ETA*(cv.x - x.x)) / wv.x;
    ov.y = (cv.y - ETA*(cv.y - x.y)) / wv.y;
    ov.z = (cv.z - ETA*(cv.z - x.z)) / wv.z;
    ov.w = (cv.w - ETA*(cv.w - x.w)) / wv.w;
    *(float4*)(c + g) = ov;
  }
}

// ---------------- kernel 0: Wt[band][e][d] = bf16(W[band][d][e]) ----------------
__global__ __launch_bounds__(256) void k_wprep(const float* __restrict__ W,
                                               unsigned short* __restrict__ Wt){
  __shared__ float tbuf[32][33];
  int band = blockIdx.y;
  int tile = blockIdx.x;             // 0..63 -> 8x8 grid of 32x32 tiles
  int td0 = (tile >> 3) * 32, te0 = (tile & 7) * 32;
  int tx = threadIdx.x & 31, ty = threadIdx.x >> 5;  // ty in 0..7
#pragma unroll
  for (int i = 0; i < 4; ++i){
    tbuf[ty*4 + i][tx] = W[(size_t)band*65536 + (size_t)(td0 + ty*4 + i)*256 + te0 + tx];
  }
  __syncthreads();
#pragma unroll
  for (int i = 0; i < 4; ++i){
    Wt[(size_t)band*65536 + (size_t)(te0 + ty*4 + i)*256 + td0 + tx] = f2bf(tbuf[tx][ty*4 + i]);
  }
}

extern "C" void kernel_launch(void* const* d_in, const int* in_sizes, int n_in,
                              void* d_out, int out_size, void* d_ws, size_t ws_size,
                              hipStream_t stream){
  const float* rho  = (const float*)d_in[0];
  const float* w    = (const float*)d_in[1];
  const float* W    = (const float*)d_in[2];
  const float* bias = (const float*)d_in[3];

  float* c = (float*)d_out;                         // scaled-coeff state lives in d_out
  unsigned short* S  = (unsigned short*)d_ws;                   // 16 MB bf16 signal
  unsigned short* Y  = S + (size_t)NB * NT * ND;                // 16 MB bf16 predicted signal
  unsigned short* Wt = Y + (size_t)NB * NT * ND;                // 1.4 MB bf16 transposed weights

  k_wprep<<<dim3(64, 11), 256, 0, stream>>>(W, Wt);
  k_idwt_first<<<dim3(16, NB), 256, 0, stream>>>(rho, w, c, S);
  k_band_gemm<<<dim3(37, NB), 256, 0, stream>>>(S, Wt, bias, Y);
  k_dwt_update_idwt<<<dim3(16, NB), 256, 0, stream>>>(Y, c, S);
  k_band_gemm<<<dim3(37, NB), 256, 0, stream>>>(S, Wt, bias, Y);
  k_dwt_final<<<dim3(16, NB), 256, 0, stream>>>(Y, c, w);
}

// Round 2
// 158.706 us; speedup vs baseline: 1.1829x; 1.1829x over previous
//
#include <hip/hip_runtime.h>
#include <hip/hip_bf16.h>

// Problem constants
#define NB 32
#define NT 1024
#define ND 256
#define DT 16      // d-columns per transform block
#define LDP 16     // LDS row pitch (floats)
#define ETA 0.1f
#define INVS 0.70710678118654752440f

typedef short bf16x8 __attribute__((ext_vector_type(8)));   // 8 bf16 in 4 VGPRs
typedef float f32x4  __attribute__((ext_vector_type(4)));

__device__ inline unsigned short f2bf(float f){
  __hip_bfloat16 h = __float2bfloat16(f);
  return *reinterpret_cast<unsigned short*>(&h);
}
__device__ inline float bf2f(unsigned short u){
  return __uint_as_float(((unsigned int)u) << 16);
}

// ---------------- fused 2-level Haar butterflies (LDS tile: NT x DT, pitch LDP) ----------------
// IDWT fused pass: a[0..N) + d[N..2N) + dd[2N..4N) -> interleaved a'[0..4N)
template<int N>
__device__ inline void idwt2_stage(float* lds, int tid){
  constexpr int ITEMS = N * DT;           // quads
  if constexpr (ITEMS >= 256) {
    constexpr int PER = ITEMS / 256;
    float v0[PER], v1[PER], v2[PER], v3[PER];
#pragma unroll
    for (int r = 0; r < PER; ++r){
      int idx = tid + r*256; int k = idx >> 4, dc = idx & 15;
      float a  = lds[k*LDP + dc];
      float d  = lds[(N + k)*LDP + dc];
      float d0 = lds[(2*N + 2*k)*LDP + dc];
      float d1 = lds[(2*N + 2*k + 1)*LDP + dc];
      float e = (a + d) * INVS, o = (a - d) * INVS;
      v0[r] = (e + d0) * INVS; v1[r] = (e - d0) * INVS;
      v2[r] = (o + d1) * INVS; v3[r] = (o - d1) * INVS;
    }
    __syncthreads();
#pragma unroll
    for (int r = 0; r < PER; ++r){
      int idx = tid + r*256; int k = idx >> 4, dc = idx & 15;
      lds[(4*k + 0)*LDP + dc] = v0[r];
      lds[(4*k + 1)*LDP + dc] = v1[r];
      lds[(4*k + 2)*LDP + dc] = v2[r];
      lds[(4*k + 3)*LDP + dc] = v3[r];
    }
    __syncthreads();
  } else {
    float v0 = 0.f, v1 = 0.f, v2 = 0.f, v3 = 0.f;
    int k = tid >> 4, dc = tid & 15;
    bool act = tid < ITEMS;
    if (act){
      float a  = lds[k*LDP + dc];
      float d  = lds[(N + k)*LDP + dc];
      float d0 = lds[(2*N + 2*k)*LDP + dc];
      float d1 = lds[(2*N + 2*k + 1)*LDP + dc];
      float e = (a + d) * INVS, o = (a - d) * INVS;
      v0 = (e + d0) * INVS; v1 = (e - d0) * INVS;
      v2 = (o + d1) * INVS; v3 = (o - d1) * INVS;
    }
    __syncthreads();
    if (act){
      lds[(4*k + 0)*LDP + dc] = v0;
      lds[(4*k + 1)*LDP + dc] = v1;
      lds[(4*k + 2)*LDP + dc] = v2;
      lds[(4*k + 3)*LDP + dc] = v3;
    }
    __syncthreads();
  }
}

__device__ inline void idwt_all(float* lds, int tid){
  idwt2_stage<1>(lds, tid);   idwt2_stage<4>(lds, tid);  idwt2_stage<16>(lds, tid);
  idwt2_stage<64>(lds, tid);  idwt2_stage<256>(lds, tid);
}

// DWT fused pass: interleaved x[0..4N) -> a[0..N) + d2[N..2N) + d1[2N..4N)
template<int N>
__device__ inline void dwt2_stage(float* lds, int tid){
  constexpr int ITEMS = N * DT;           // quads
  if constexpr (ITEMS >= 256) {
    constexpr int PER = ITEMS / 256;
    float va[PER], vd2[PER], vd1a[PER], vd1b[PER];
#pragma unroll
    for (int r = 0; r < PER; ++r){
      int idx = tid + r*256; int k = idx >> 4, dc = idx & 15;
      float x0 = lds[(4*k + 0)*LDP + dc];
      float x1 = lds[(4*k + 1)*LDP + dc];
      float x2 = lds[(4*k + 2)*LDP + dc];
      float x3 = lds[(4*k + 3)*LDP + dc];
      float a0 = (x0 + x1) * INVS, a1 = (x2 + x3) * INVS;
      vd1a[r] = (x0 - x1) * INVS; vd1b[r] = (x2 - x3) * INVS;
      va[r]  = (a0 + a1) * INVS;  vd2[r]  = (a0 - a1) * INVS;
    }
    __syncthreads();
#pragma unroll
    for (int r = 0; r < PER; ++r){
      int idx = tid + r*256; int k = idx >> 4, dc = idx & 15;
      lds[k*LDP + dc]                 = va[r];
      lds[(N + k)*LDP + dc]           = vd2[r];
      lds[(2*N + 2*k)*LDP + dc]       = vd1a[r];
      lds[(2*N + 2*k + 1)*LDP + dc]   = vd1b[r];
    }
    __syncthreads();
  } else {
    float va = 0.f, vd2 = 0.f, vd1a = 0.f, vd1b = 0.f;
    int k = tid >> 4, dc = tid & 15;
    bool act = tid < ITEMS;
    if (act){
      float x0 = lds[(4*k + 0)*LDP + dc];
      float x1 = lds[(4*k + 1)*LDP + dc];
      float x2 = lds[(4*k + 2)*LDP + dc];
      float x3 = lds[(4*k + 3)*LDP + dc];
      float a0 = (x0 + x1) * INVS, a1 = (x2 + x3) * INVS;
      vd1a = (x0 - x1) * INVS; vd1b = (x2 - x3) * INVS;
      va  = (a0 + a1) * INVS;  vd2  = (a0 - a1) * INVS;
    }
    __syncthreads();
    if (act){
      lds[k*LDP + dc]                 = va;
      lds[(N + k)*LDP + dc]           = vd2;
      lds[(2*N + 2*k)*LDP + dc]       = vd1a;
      lds[(2*N + 2*k + 1)*LDP + dc]   = vd1b;
    }
    __syncthreads();
  }
}

__device__ inline void dwt_all(float* lds, int tid){
  dwt2_stage<256>(lds, tid); dwt2_stage<64>(lds, tid); dwt2_stage<16>(lds, tid);
  dwt2_stage<4>(lds, tid);   dwt2_stage<1>(lds, tid);
}

// ---------------- kernel A: c = w.rho (write), S = bf16(IDWT(c)) ----------------
__global__ __launch_bounds__(256) void k_idwt_first(const float* __restrict__ rho,
                                                    const float* __restrict__ w,
                                                    float* __restrict__ c,
                                                    unsigned short* __restrict__ S){
  __shared__ float lds[NT * LDP];
  int tid = threadIdx.x;
  int b = blockIdx.y;
  int d0 = blockIdx.x * DT;
  size_t base = ((size_t)b * NT) * ND;
#pragma unroll
  for (int r = 0; r < 16; ++r){
    int q = tid + r*256; int t = q >> 2, qq = q & 3;
    size_t g = base + (size_t)t*ND + d0 + qq*4;
    float4 rv = *(const float4*)(rho + g);
    float4 wv = *(const float4*)(w + (size_t)t*ND + d0 + qq*4);
    float4 cv; cv.x = rv.x*wv.x; cv.y = rv.y*wv.y; cv.z = rv.z*wv.z; cv.w = rv.w*wv.w;
    *(float4*)(c + g) = cv;
    *(float4*)(&lds[t*LDP + qq*4]) = cv;
  }
  __syncthreads();
  idwt_all(lds, tid);
#pragma unroll
  for (int r = 0; r < 16; ++r){
    int q = tid + r*256; int t = q >> 2, qq = q & 3;
    size_t g = base + (size_t)t*ND + d0 + qq*4;
    float4 v = *(float4*)(&lds[t*LDP + qq*4]);
    ushort4 o; o.x = f2bf(v.x); o.y = f2bf(v.y); o.z = f2bf(v.z); o.w = f2bf(v.w);
    *(ushort4*)(S + g) = o;
  }
}

// ---------------- kernel B/D: per-band GEMM with register-held B, TM=4 tiles/block ----------------
// Wt is W transposed per band: Wt[band][e][d] = W[band][d][e] (bf16)
// Job space: 32-row M-tiles grouped by band (same W). Uniform bands 6..10 cover t>=32;
// masked bands 0..5 compute rows [0,32) with row predicate.
__global__ __launch_bounds__(256, 2) void k_band_gemm(const unsigned short* __restrict__ S,
                                                      const unsigned short* __restrict__ Wt,
                                                      const float* __restrict__ bias,
                                                      unsigned short* __restrict__ Y){
  int bx = blockIdx.x;  // 0..295
  int wv = threadIdx.x >> 6, lane = threadIdx.x & 63;
  int row = lane & 15, kg = lane >> 4;
  int band, jbase; bool masked = false;
  if      (bx <   8){ band =  6; jbase = bx*4; }
  else if (bx <  24){ band =  7; jbase = (bx-8)*4; }
  else if (bx <  56){ band =  8; jbase = (bx-24)*4; }
  else if (bx < 120){ band =  9; jbase = (bx-56)*4; }
  else if (bx < 248){ band = 10; jbase = (bx-120)*4; }
  else { masked = true; int mb = bx-248; band = mb>>3; jbase = (mb&7)*4; }

  int n0 = wv * 64;
  const unsigned short* Wb = Wt + (size_t)band * 65536;

  // B panel: 64 cols x K=256, held in registers (128 VGPR)
  bf16x8 breg[8][4];
#pragma unroll
  for (int kk = 0; kk < 8; ++kk)
#pragma unroll
    for (int ni = 0; ni < 4; ++ni)
      breg[kk][ni] = *(const bf16x8*)(Wb + (size_t)(n0 + 16*ni + row)*256 + kk*32 + kg*8);

  float bv[4];
#pragma unroll
  for (int ni = 0; ni < 4; ++ni) bv[ni] = bias[band*256 + n0 + 16*ni + row];

  int lo = 0, hi = 0;
  if (masked){
    lo = (band == 0) ? 0 : (1 << (band - 1));
    hi = (band == 0) ? 1 : (1 << band);
  }
  int shift = masked ? 0 : (band - 6);
  int tstart = masked ? 0 : (32 << shift);

  for (int m = 0; m < 4; ++m){
    int j = jbase + m;
    int bb, t0;
    if (masked){ bb = j; t0 = 0; }
    else { bb = j >> shift; t0 = tstart + (j & ((1 << shift) - 1)) * 32; }

    f32x4 acc[2][4];
#pragma unroll
    for (int mi = 0; mi < 2; ++mi)
#pragma unroll
      for (int ni = 0; ni < 4; ++ni) acc[mi][ni] = (f32x4){0.f, 0.f, 0.f, 0.f};

    size_t arow0 = ((size_t)bb * NT + t0 + row) * ND;
#pragma unroll
    for (int kk = 0; kk < 8; ++kk){
      int k = kk*32 + kg*8;
      bf16x8 a0 = *(const bf16x8*)(S + arow0 + k);
      bf16x8 a1 = *(const bf16x8*)(S + arow0 + 16*ND + k);
#pragma unroll
      for (int ni = 0; ni < 4; ++ni){
        acc[0][ni] = __builtin_amdgcn_mfma_f32_16x16x32_bf16(a0, breg[kk][ni], acc[0][ni], 0, 0, 0);
        acc[1][ni] = __builtin_amdgcn_mfma_f32_16x16x32_bf16(a1, breg[kk][ni], acc[1][ni], 0, 0, 0);
      }
    }
#pragma unroll
    for (int ni = 0; ni < 4; ++ni){
#pragma unroll
      for (int mi = 0; mi < 2; ++mi){
#pragma unroll
        for (int jj = 0; jj < 4; ++jj){
          int t = t0 + 16*mi + kg*4 + jj;   // C/D: row=(lane>>4)*4+reg, col=lane&15
          if (!masked || (t >= lo && t < hi)){
            Y[((size_t)bb*NT + t)*ND + n0 + 16*ni + row] = f2bf(acc[mi][ni][jj] + bv[ni]);
          }
        }
      }
    }
  }
}

// ---------------- kernel C: C2 = DWT(Y); c' = c - eta*(c - C2) (write back); S = bf16(IDWT(c')) ----------------
__global__ __launch_bounds__(256) void k_dwt_update_idwt(const unsigned short* __restrict__ Y,
                                                         float* __restrict__ c,
                                                         unsigned short* __restrict__ S){
  __shared__ float lds[NT * LDP];
  int tid = threadIdx.x;
  int b = blockIdx.y;
  int d0 = blockIdx.x * DT;
  size_t base = ((size_t)b * NT) * ND;
#pragma unroll
  for (int r = 0; r < 16; ++r){
    int q = tid + r*256; int t = q >> 2, qq = q & 3;
    size_t g = base + (size_t)t*ND + d0 + qq*4;
    ushort4 yv = *(const ushort4*)(Y + g);
    lds[t*LDP + qq*4 + 0] = bf2f(yv.x);
    lds[t*LDP + qq*4 + 1] = bf2f(yv.y);
    lds[t*LDP + qq*4 + 2] = bf2f(yv.z);
    lds[t*LDP + qq*4 + 3] = bf2f(yv.w);
  }
  __syncthreads();
  dwt_all(lds, tid);
#pragma unroll
  for (int r = 0; r < 16; ++r){
    int q = tid + r*256; int t = q >> 2, qq = q & 3;
    size_t g = base + (size_t)t*ND + d0 + qq*4;
    float4 cv = *(const float4*)(c + g);
    float4 x  = *(float4*)(&lds[t*LDP + qq*4]);
    float4 nc;
    nc.x = cv.x - ETA*(cv.x - x.x);
    nc.y = cv.y - ETA*(cv.y - x.y);
    nc.z = cv.z - ETA*(cv.z - x.z);
    nc.w = cv.w - ETA*(cv.w - x.w);
    *(float4*)(c + g) = nc;
    *(float4*)(&lds[t*LDP + qq*4]) = nc;
  }
  __syncthreads();
  idwt_all(lds, tid);
#pragma unroll
  for (int r = 0; r < 16; ++r){
    int q = tid + r*256; int t = q >> 2, qq = q & 3;
    size_t g = base + (size_t)t*ND + d0 + qq*4;
    float4 v = *(float4*)(&lds[t*LDP + qq*4]);
    ushort4 o; o.x = f2bf(v.x); o.y = f2bf(v.y); o.z = f2bf(v.z); o.w = f2bf(v.w);
    *(ushort4*)(S + g) = o;
  }
}

// ---------------- kernel E: C2 = DWT(Y); out = (c - eta*(c - C2)) / w ----------------
__global__ __launch_bounds__(256) void k_dwt_final(const unsigned short* __restrict__ Y,
                                                   float* __restrict__ c,
                                                   const float* __restrict__ w){
  __shared__ float lds[NT * LDP];
  int tid = threadIdx.x;
  int b = blockIdx.y;
  int d0 = blockIdx.x * DT;
  size_t base = ((size_t)b * NT) * ND;
#pragma unroll
  for (int r = 0; r < 16; ++r){
    int q = tid + r*256; int t = q >> 2, qq = q & 3;
    size_t g = base + (size_t)t*ND + d0 + qq*4;
    ushort4 yv = *(const ushort4*)(Y + g);
    lds[t*LDP + qq*4 + 0] = bf2f(yv.x);
    lds[t*LDP + qq*4 + 1] = bf2f(yv.y);
    lds[t*LDP + qq*4 + 2] = bf2f(yv.z);
    lds[t*LDP + qq*4 + 3] = bf2f(yv.w);
  }
  __syncthreads();
  dwt_all(lds, tid);
#pragma unroll
  for (int r = 0; r < 16; ++r){
    int q = tid + r*256; int t = q >> 2, qq = q & 3;
    size_t g = base + (size_t)t*ND + d0 + qq*4;
    float4 cv = *(const float4*)(c + g);
    float4 x  = *(float4*)(&lds[t*LDP + qq*4]);
    size_t wg = (size_t)t*ND + d0 + qq*4;
    float4 wv = *(const float4*)(w + wg);
    float4 ov;
    ov.x = (cv.x - ETA*(cv.x - x.x)) / wv.x;
    ov.y = (cv.y - ETA*(cv.y - x.y)) / wv.y;
    ov.z = (cv.z - ETA*(cv.z - x.z)) / wv.z;
    ov.w = (cv.w - ETA*(cv.w - x.w)) / wv.w;
    *(float4*)(c + g) = ov;
  }
}

// ---------------- kernel 0: Wt[band][e][d] = bf16(W[band][d][e]) ----------------
__global__ __launch_bounds__(256) void k_wprep(const float* __restrict__ W,
                                               unsigned short* __restrict__ Wt){
  __shared__ float tbuf[32][33];
  int band = blockIdx.y;
  int tile = blockIdx.x;             // 0..63 -> 8x8 grid of 32x32 tiles
  int td0 = (tile >> 3) * 32, te0 = (tile & 7) * 32;
  int tx = threadIdx.x & 31, ty = threadIdx.x >> 5;  // ty in 0..7
#pragma unroll
  for (int i = 0; i < 4; ++i){
    tbuf[ty*4 + i][tx] = W[(size_t)band*65536 + (size_t)(td0 + ty*4 + i)*256 + te0 + tx];
  }
  __syncthreads();
#pragma unroll
  for (int i = 0; i < 4; ++i){
    Wt[(size_t)band*65536 + (size_t)(te0 + ty*4 + i)*256 + td0 + tx] = f2bf(tbuf[tx][ty*4 + i]);
  }
}

extern "C" void kernel_launch(void* const* d_in, const int* in_sizes, int n_in,
                              void* d_out, int out_size, void* d_ws, size_t ws_size,
                              hipStream_t stream){
  const float* rho  = (const float*)d_in[0];
  const float* w    = (const float*)d_in[1];
  const float* W    = (const float*)d_in[2];
  const float* bias = (const float*)d_in[3];

  float* c = (float*)d_out;                         // scaled-coeff state lives in d_out
  unsigned short* S  = (unsigned short*)d_ws;                   // 16 MB bf16 signal
  unsigned short* Y  = S + (size_t)NB * NT * ND;                // 16 MB bf16 predicted signal
  unsigned short* Wt = Y + (size_t)NB * NT * ND;                // 1.4 MB bf16 transposed weights

  k_wprep<<<dim3(64, 11), 256, 0, stream>>>(W, Wt);
  k_idwt_first<<<dim3(16, NB), 256, 0, stream>>>(rho, w, c, S);
  k_band_gemm<<<dim3(296, 1), 256, 0, stream>>>(S, Wt, bias, Y);
  k_dwt_update_idwt<<<dim3(16, NB), 256, 0, stream>>>(Y, c, S);
  k_band_gemm<<<dim3(296, 1), 256, 0, stream>>>(S, Wt, bias, Y);
  k_dwt_final<<<dim3(16, NB), 256, 0, stream>>>(Y, c, w);
}